// Round 1
// baseline (3393.380 us; speedup 1.0000x reference)
//
#include <hip/hip_runtime.h>
#include <cstddef>

// ---- problem constants ----
constexpr int kT   = 1024;
constexpr int kB   = 64;
constexpr int kDIN = 17;
constexpr int kHM  = 150;   // main hidden (per dir)
constexpr int kGM  = 450;   // 3*kHM
constexpr int kHH  = 128;   // hier hidden (per dir)
constexpr int kGH  = 384;   // 3*kHH
constexpr int kM   = 16;    // measure length
constexpr int kNM  = 64;    // measures per sequence
constexpr int kD2  = 300;   // 2*kHM
constexpr int kDH2 = 256;   // 2*kHH
constexpr int kNP  = 35;
constexpr int kNK  = 15;

// ---- workspace layout (float offsets, all 16-float aligned) ----
constexpr size_t OFF_RNN    = 0;          // [1024][64][300]   19,660,800
constexpr size_t OFF_HV     = 19660800;   // [4096][16][256]   16,777,216
constexpr size_t OFF_CTX    = 36438016;   // [4096][256]        1,048,576
constexpr size_t OFF_PT     = 37486592;   // [256][256]            65,536
constexpr size_t OFF_U      = 37552128;   // [256]
constexpr size_t OFF_W      = 37552384;   // [256]
constexpr size_t OFF_C0     = 37552640;   // [16]
constexpr size_t OFF_ACC    = 37552656;   // [16] (sp,cp,sk,ck)
constexpr size_t OFF_KSLOGP = 37552672;   // [4096][15]            61,440
constexpr size_t OFF_CLOG   = 37614112;   // [4096][35]           143,360
constexpr size_t OFF_MWIHT  = 37757472;   // [2][17][450]          15,312
constexpr size_t OFF_MWHHT  = 37772784;   // [2][150][450]        135,008
constexpr size_t OFF_HWIHT  = 37907792;   // [2][300][384]        230,400
constexpr size_t OFF_HWHHT  = 38138192;   // [2][128][384]         98,304
// total 38,236,496 floats = 152.9 MB

// ---------------------------------------------------------------------------
// generic (sub-)transpose: dst[c][r] = src[r][c0 + c]; dst is [Cn][R]
__global__ void k_transpose(const float* __restrict__ src, float* __restrict__ dst,
                            int R, int Csrc, int c0, int Cn) {
  int i = blockIdx.x * blockDim.x + threadIdx.x;
  if (i < R * Cn) {
    int r = i / Cn, c = i - r * Cn;
    dst[c * R + r] = src[r * Csrc + c0 + c];
  }
}

// PT[e][c] = sum_a Wq[a][c]*Wv[a][e]   (= (Wq^T Wv)[c][e])
__global__ void k_pt(const float* __restrict__ Wq, const float* __restrict__ Wv,
                     float* __restrict__ PT) {
  const int e = blockIdx.x, c = threadIdx.x;
  float acc = 0.f;
  for (int a = 0; a < 256; a++) acc += Wq[a * 256 + c] * Wv[a * 256 + e];
  PT[e * 256 + c] = acc;
}

// u[c] = sum_a Wq[a][c]*bv[a]; w[e] = sum_a bq[a]*Wv[a][e]; c0 = bq.bv; zero accums
__global__ void k_small(const float* __restrict__ Wq, const float* __restrict__ bq,
                        const float* __restrict__ Wv, const float* __restrict__ bv,
                        float* __restrict__ u, float* __restrict__ w,
                        float* __restrict__ c0, float* __restrict__ acc) {
  const int a = threadIdx.x; // 256
  float us = 0.f, ws = 0.f;
  for (int j = 0; j < 256; j++) {
    us += Wq[j * 256 + a] * bv[j];
    ws += bq[j] * Wv[j * 256 + a];
  }
  u[a] = us; w[a] = ws;
  if (a == 0) {
    float c = 0.f;
    for (int j = 0; j < 256; j++) c += bq[j] * bv[j];
    c0[0] = c;
    acc[0] = acc[1] = acc[2] = acc[3] = 0.f;
  }
}

// ---------------------------------------------------------------------------
// Main bi-GRU: one block per (batch, dir). Weights in registers (thread=gate),
// h broadcast from LDS. 1024 sequential steps, 2 barriers/step.
__global__ __launch_bounds__(512, 2) void k_main_gru(
    const float* __restrict__ x,      // [1024][64][17]
    const float* __restrict__ WihT,   // [2][17][450]
    const float* __restrict__ WhhT,   // [2][150][450]
    const float* __restrict__ bihf, const float* __restrict__ bhhf,
    const float* __restrict__ bihb, const float* __restrict__ bhhb,
    float* __restrict__ rnn)          // [1024][64][300]
{
  const int d = blockIdx.x & 1;
  const int b = blockIdx.x >> 1;
  const int g = threadIdx.x;
  __shared__ __align__(16) float h_s[152];
  __shared__ __align__(16) float x_s[2][20];
  __shared__ float Ssum[300];
  __shared__ float INs[152];
  __shared__ float HNs[152];
  float wih[20], whh[152];
  float bi = 0.f, bh = 0.f;
  const float* WihTd = WihT + (size_t)d * (kDIN * kGM);
  const float* WhhTd = WhhT + (size_t)d * (kHM * kGM);
  if (g < kGM) {
#pragma unroll
    for (int k = 0; k < kDIN; k++) wih[k] = WihTd[k * kGM + g];
    wih[17] = wih[18] = wih[19] = 0.f;
#pragma unroll
    for (int k = 0; k < kHM; k++) whh[k] = WhhTd[k * kGM + g];
    whh[150] = whh[151] = 0.f;
    bi = d ? bihb[g] : bihf[g];
    bh = d ? bhhb[g] : bhhf[g];
  }
  if (g < 152) h_s[g] = 0.f;
  if (g < kDIN) {
    int t0 = d ? (kT - 1) : 0;
    x_s[0][g] = x[(t0 * kB + b) * kDIN + g];
  }
  if (g >= 64 && g < 67) { x_s[0][17 + (g - 64)] = 0.f; x_s[1][17 + (g - 64)] = 0.f; }
  __syncthreads();

  for (int t = 0; t < kT; t++) {
    const int tx = d ? (kT - 1 - t) : t;
    const int buf = t & 1;
    if (g < kGM) {
      float a0 = 0.f, a1 = 0.f, a2 = 0.f, a3 = 0.f;
#pragma unroll
      for (int k = 0; k < 152; k += 4) {
        const float4 hq = *(const float4*)&h_s[k];
        a0 += whh[k] * hq.x; a1 += whh[k + 1] * hq.y;
        a2 += whh[k + 2] * hq.z; a3 += whh[k + 3] * hq.w;
      }
      const float ah = (a0 + a1) + (a2 + a3) + bh;
      float i0 = 0.f, i1 = 0.f, i2 = 0.f, i3 = 0.f;
#pragma unroll
      for (int k = 0; k < 20; k += 4) {
        const float4 xq = *(const float4*)&x_s[buf][k];
        i0 += wih[k] * xq.x; i1 += wih[k + 1] * xq.y;
        i2 += wih[k + 2] * xq.z; i3 += wih[k + 3] * xq.w;
      }
      const float ai = (i0 + i1) + (i2 + i3) + bi;
      if (g < 300) Ssum[g] = ai + ah;
      else { INs[g - 300] = ai; HNs[g - 300] = ah; }
    }
    __syncthreads();
    if (t + 1 < kT && g >= 256 && g < 256 + kDIN) {
      const int tn = d ? (kT - 2 - t) : (t + 1);
      x_s[buf ^ 1][g - 256] = x[(tn * kB + b) * kDIN + (g - 256)];
    }
    if (g < kHM) {
      const float r = 1.f / (1.f + __expf(-Ssum[g]));
      const float z = 1.f / (1.f + __expf(-Ssum[150 + g]));
      const float n = tanhf(INs[g] + r * HNs[g]);
      const float hn = (1.f - z) * n + z * h_s[g];
      h_s[g] = hn;
      rnn[(tx * kB + b) * kD2 + d * kHM + g] = hn;
    }
    __syncthreads();
  }
}

// ---------------------------------------------------------------------------
// Hier bi-GRU, fused input-gate GEMM. Block = (dir, 16 bn), 384 threads:
// thread = (gate-pair p, k-half). Weights streamed coalesced from L2,
// x/h staged in LDS (float4 broadcast reads), pair-reduce via shfl_xor(1).
__global__ __launch_bounds__(384, 3) void k_hier(
    const float* __restrict__ rnn,    // [1024][64][300]
    const float* __restrict__ WihT,   // [2][300][384]
    const float* __restrict__ WhhT,   // [2][128][384]
    const float* __restrict__ bihf, const float* __restrict__ bhhf,
    const float* __restrict__ bihb, const float* __restrict__ bhhb,
    float* __restrict__ hv)           // [4096][16][256]
{
  const int d = blockIdx.x & 1;
  const int bn0 = (blockIdx.x >> 1) * 16;
  const int tid = threadIdx.x;
  const int p = tid >> 1, half = tid & 1;
  const int g0 = 2 * p, g1 = 2 * p + 1;
  __shared__ __align__(16) float x_s[16][304];
  __shared__ __align__(16) float h_s[16][128];
  __shared__ __align__(16) float Ssum[16][256];
  __shared__ __align__(16) float INs[16][128];
  __shared__ __align__(16) float HNs[16][128];
  const float* WihTd = WihT + (size_t)d * (kD2 * kGH);
  const float* WhhTd = WhhT + (size_t)d * (kHH * kGH);
  const float* bih = d ? bihb : bihf;
  const float* bhh = d ? bhhb : bhhf;
  const float bi0 = bih[g0], bi1 = bih[g1], bh0 = bhh[g0], bh1 = bhh[g1];
  for (int i = tid; i < 16 * kHH; i += 384) ((float*)h_s)[i] = 0.f;
  __syncthreads();
  const int kin0 = half ? 152 : 0;
  const int kinN = half ? 148 : 152;
  const int kh0 = half * 64;
  for (int m = 0; m < kM; m++) {
    const int mx = d ? (kM - 1 - m) : m;
    for (int i = tid; i < 16 * kD2; i += 384) {
      const int r = i / kD2, c = i - r * kD2;
      const int bn = bn0 + r, bb = bn >> 6, nn = bn & 63;
      x_s[r][c] = rnn[((nn * kM + mx) * kB + bb) * kD2 + c];
    }
    __syncthreads();
    float ai0[16], ai1[16], ah0[16], ah1[16];
#pragma unroll
    for (int r = 0; r < 16; r++) { ai0[r] = 0.f; ai1[r] = 0.f; ah0[r] = 0.f; ah1[r] = 0.f; }
    for (int kc = 0; kc < kinN; kc += 4) {
      const int k = kin0 + kc;
      const float2 w0 = *(const float2*)&WihTd[(k + 0) * kGH + g0];
      const float2 w1 = *(const float2*)&WihTd[(k + 1) * kGH + g0];
      const float2 w2 = *(const float2*)&WihTd[(k + 2) * kGH + g0];
      const float2 w3 = *(const float2*)&WihTd[(k + 3) * kGH + g0];
#pragma unroll
      for (int r = 0; r < 16; r++) {
        const float4 xq = *(const float4*)&x_s[r][k];
        ai0[r] += w0.x * xq.x + w1.x * xq.y + w2.x * xq.z + w3.x * xq.w;
        ai1[r] += w0.y * xq.x + w1.y * xq.y + w2.y * xq.z + w3.y * xq.w;
      }
    }
#pragma unroll 4
    for (int kc = 0; kc < 64; kc += 4) {
      const int k = kh0 + kc;
      const float2 w0 = *(const float2*)&WhhTd[(k + 0) * kGH + g0];
      const float2 w1 = *(const float2*)&WhhTd[(k + 1) * kGH + g0];
      const float2 w2 = *(const float2*)&WhhTd[(k + 2) * kGH + g0];
      const float2 w3 = *(const float2*)&WhhTd[(k + 3) * kGH + g0];
#pragma unroll
      for (int r = 0; r < 16; r++) {
        const float4 hq = *(const float4*)&h_s[r][k];
        ah0[r] += w0.x * hq.x + w1.x * hq.y + w2.x * hq.z + w3.x * hq.w;
        ah1[r] += w0.y * hq.x + w1.y * hq.y + w2.y * hq.z + w3.y * hq.w;
      }
    }
#pragma unroll
    for (int r = 0; r < 16; r++) {
      const float v0 = ai0[r] + __shfl_xor(ai0[r], 1);
      const float v1 = ai1[r] + __shfl_xor(ai1[r], 1);
      const float u0 = ah0[r] + __shfl_xor(ah0[r], 1);
      const float u1 = ah1[r] + __shfl_xor(ah1[r], 1);
      if (half == 0) {
        if (g0 < 256) {
          *(float2*)&Ssum[r][g0] = make_float2(v0 + u0 + bi0 + bh0, v1 + u1 + bi1 + bh1);
        } else {
          *(float2*)&INs[r][g0 - 256] = make_float2(v0 + bi0, v1 + bi1);
          *(float2*)&HNs[r][g0 - 256] = make_float2(u0 + bh0, u1 + bh1);
        }
      }
    }
    __syncthreads();
    for (int i = tid; i < 16 * kHH; i += 384) {
      const int r = i >> 7, j = i & 127;
      const float rr = 1.f / (1.f + __expf(-Ssum[r][j]));
      const float zz = 1.f / (1.f + __expf(-Ssum[r][128 + j]));
      const float nn = tanhf(INs[r][j] + rr * HNs[r][j]);
      const float hnew = (1.f - zz) * nn + zz * h_s[r][j];
      h_s[r][j] = hnew;
      hv[((size_t)(bn0 + r) * kM + mx) * kDH2 + d * kHH + j] = hnew;
    }
    __syncthreads();
  }
}

// ---------------------------------------------------------------------------
// Attention (collapsed): per n compute T = P*h_m, scores, softmax, ctx.
__global__ void k_attn(const float* __restrict__ hv, const float* __restrict__ PT,
                       const float* __restrict__ u, const float* __restrict__ w,
                       const float* __restrict__ c0p, float* __restrict__ ctx) {
  const int tid = threadIdx.x; // 256
  __shared__ __align__(16) float hvs[16][256];
  __shared__ __align__(16) float Ts[16][260];
  __shared__ float As[16][17];
  __shared__ float uh[16], wh[16], SM[16];
  const float c0 = c0p[0];
  for (int ni = 0; ni < 16; ni++) {
    const int n = blockIdx.x * 16 + ni;
    for (int i = tid; i < 4096; i += 256) hvs[i >> 8][i & 255] = hv[(size_t)n * 4096 + i];
    __syncthreads();
    float acc[16];
#pragma unroll
    for (int m2 = 0; m2 < 16; m2++) acc[m2] = 0.f;
    for (int k = 0; k < 256; k += 4) {
      const float p0 = PT[(k + 0) * 256 + tid];
      const float p1 = PT[(k + 1) * 256 + tid];
      const float p2 = PT[(k + 2) * 256 + tid];
      const float p3 = PT[(k + 3) * 256 + tid];
#pragma unroll
      for (int m2 = 0; m2 < 16; m2++) {
        const float4 hq = *(const float4*)&hvs[m2][k];
        acc[m2] += p0 * hq.x + p1 * hq.y + p2 * hq.z + p3 * hq.w;
      }
    }
#pragma unroll
    for (int m2 = 0; m2 < 16; m2++) Ts[m2][tid] = acc[m2];
    if (tid < 16) {
      float s = 0.f;
      for (int a = 0; a < 256; a++) s += u[a] * hvs[tid][a];
      uh[tid] = s;
    } else if (tid < 32) {
      float s = 0.f;
      for (int a = 0; a < 256; a++) s += w[a] * hvs[tid - 16][a];
      wh[tid - 16] = s;
    }
    __syncthreads();
    const int l = tid >> 4, mm = tid & 15;
    float sc = c0 + uh[l] + wh[mm];
    for (int a = 0; a < 256; a += 4) {
      const float4 hq = *(const float4*)&hvs[l][a];
      const float4 tq = *(const float4*)&Ts[mm][a];
      sc += hq.x * tq.x + hq.y * tq.y + hq.z * tq.z + hq.w * tq.w;
    }
    float mxv = sc;
#pragma unroll
    for (int o = 8; o >= 1; o >>= 1) mxv = fmaxf(mxv, __shfl_xor(mxv, o, 16));
    const float e = __expf(sc - mxv);
    float se = e;
#pragma unroll
    for (int o = 8; o >= 1; o >>= 1) se += __shfl_xor(se, o, 16);
    As[l][mm] = e / se;
    __syncthreads();
    if (tid < 16) {
      float s = 0.f;
      for (int l2 = 0; l2 < 16; l2++) s += As[l2][tid];
      SM[tid] = s;
    }
    __syncthreads();
    float cv = 0.f;
#pragma unroll
    for (int m2 = 0; m2 < 16; m2++) cv += SM[m2] * hvs[m2][tid];
    ctx[(size_t)n * 256 + tid] = cv;
    __syncthreads();
  }
}

// ---------------------------------------------------------------------------
// Per-(b,measure) logit parts: ctx contribution to pitch logits (+bp) and
// full ks log-probs.
__global__ void k_ctxlog(const float* __restrict__ ctx, const float* __restrict__ Wp,
                         const float* __restrict__ bp, const float* __restrict__ Wk,
                         const float* __restrict__ bk,
                         float* __restrict__ ctx_logits, float* __restrict__ ks_logp) {
  const int bn = blockIdx.x, lane = threadIdx.x; // 64 threads
  __shared__ __align__(16) float W2[35][260];
  __shared__ __align__(16) float Wks[15][260];
  __shared__ __align__(16) float cs[256];
  for (int i = lane; i < 35 * 256; i += 64) { const int j = i >> 8, k = i & 255; W2[j][k] = Wp[j * 556 + 300 + k]; }
  for (int i = lane; i < 15 * 256; i += 64) { const int j = i >> 8, k = i & 255; Wks[j][k] = Wk[j * 256 + k]; }
  for (int i = lane; i < 256; i += 64) cs[i] = ctx[(size_t)bn * 256 + i];
  __syncthreads();
  if (lane < 35) {
    float a0 = 0.f, a1 = 0.f, a2 = 0.f, a3 = 0.f;
    for (int k = 0; k < 256; k += 4) {
      const float4 wq = *(const float4*)&W2[lane][k];
      const float4 cq = *(const float4*)&cs[k];
      a0 += wq.x * cq.x; a1 += wq.y * cq.y; a2 += wq.z * cq.z; a3 += wq.w * cq.w;
    }
    ctx_logits[bn * kNP + lane] = (a0 + a1) + (a2 + a3) + bp[lane];
  }
  float kk = -1e30f;
  if (lane < 15) {
    float a0 = 0.f, a1 = 0.f, a2 = 0.f, a3 = 0.f;
    for (int k = 0; k < 256; k += 4) {
      const float4 wq = *(const float4*)&Wks[lane][k];
      const float4 cq = *(const float4*)&cs[k];
      a0 += wq.x * cq.x; a1 += wq.y * cq.y; a2 += wq.z * cq.z; a3 += wq.w * cq.w;
    }
    kk = (a0 + a1) + (a2 + a3) + bk[lane];
  }
  float mxv = kk;
#pragma unroll
  for (int o = 8; o >= 1; o >>= 1) mxv = fmaxf(mxv, __shfl_xor(mxv, o, 16));
  const float e = (lane < 15) ? __expf(kk - mxv) : 0.f;
  float se = e;
#pragma unroll
  for (int o = 8; o >= 1; o >>= 1) se += __shfl_xor(se, o, 16);
  if (lane < 15) ks_logp[bn * kNK + lane] = kk - mxv - __logf(se);
}

// ---------------------------------------------------------------------------
// Pitch CE (rnn part of logits computed here, ctx part gathered) + ks CE gather.
__global__ __launch_bounds__(256) void k_loss(
    const float* __restrict__ rnn, const float* __restrict__ Wp,
    const float* __restrict__ ctx_logits, const float* __restrict__ ks_logp,
    const int* __restrict__ pitches, const int* __restrict__ kss,
    float* __restrict__ acc) {
  __shared__ __align__(16) float W1[35][308];
  __shared__ __align__(16) float xrs[4][304];
  __shared__ float red[4][4];
  const int tid = threadIdx.x, w = tid >> 6, lane = tid & 63;
  for (int i = tid; i < 35 * 300; i += 256) {
    const int j = i / 300, k = i - j * 300;
    W1[j][k] = Wp[j * 556 + k];
  }
  __syncthreads();
  float sp = 0.f, cp = 0.f, sk = 0.f, ck = 0.f;
  for (int it = 0; it < 64; it++) {
    const int row = blockIdx.x * 256 + it * 4 + w; // row = t*64 + b
    const int t = row >> 6, b = row & 63;
    const float* rp = rnn + (size_t)row * kD2;
    for (int i = lane; i < kD2; i += 64) xrs[w][i] = rp[i];
    __syncthreads();
    const int bn = b * 64 + (t >> 4);
    float lg = -1e30f;
    if (lane < 35) {
      float a0 = 0.f, a1 = 0.f, a2 = 0.f, a3 = 0.f;
      for (int k = 0; k < kD2; k += 4) {
        const float4 wq = *(const float4*)&W1[lane][k];
        const float4 xq = *(const float4*)&xrs[w][k];
        a0 += wq.x * xq.x; a1 += wq.y * xq.y; a2 += wq.z * xq.z; a3 += wq.w * xq.w;
      }
      lg = (a0 + a1) + (a2 + a3) + ctx_logits[bn * kNP + lane];
    }
    float mxv = lg;
#pragma unroll
    for (int o = 32; o >= 1; o >>= 1) mxv = fmaxf(mxv, __shfl_xor(mxv, o, 64));
    const float e = (lane < 35) ? __expf(lg - mxv) : 0.f;
    float se = e;
#pragma unroll
    for (int o = 32; o >= 1; o >>= 1) se += __shfl_xor(se, o, 64);
    const int tp2 = pitches[row];
    if (tp2 != 34) { sp += (mxv + __logf(se)) - __shfl(lg, tp2, 64); cp += 1.f; }
    const int tk = kss[row];
    if (tk != 14) { sk -= ks_logp[bn * kNK + tk]; ck += 1.f; }
    __syncthreads();
  }
  if (lane == 0) { red[w][0] = sp; red[w][1] = cp; red[w][2] = sk; red[w][3] = ck; }
  __syncthreads();
  if (tid == 0) {
    float a0 = 0.f, a1 = 0.f, a2 = 0.f, a3 = 0.f;
    for (int q = 0; q < 4; q++) { a0 += red[q][0]; a1 += red[q][1]; a2 += red[q][2]; a3 += red[q][3]; }
    atomicAdd(&acc[0], a0); atomicAdd(&acc[1], a1);
    atomicAdd(&acc[2], a2); atomicAdd(&acc[3], a3);
  }
}

__global__ void k_final(const float* __restrict__ acc, float* __restrict__ out) {
  out[0] = acc[0] / fmaxf(acc[1], 1.f) + acc[2] / fmaxf(acc[3], 1.f);
}

// ---------------------------------------------------------------------------
extern "C" void kernel_launch(void* const* d_in, const int* in_sizes, int n_in,
                              void* d_out, int out_size, void* d_ws, size_t ws_size,
                              hipStream_t stream) {
  (void)in_sizes; (void)n_in; (void)out_size; (void)ws_size;
  const float* sent    = (const float*)d_in[0];
  const int*   pitches = (const int*)d_in[1];
  const int*   kss     = (const int*)d_in[2];
  const float* mWih_f  = (const float*)d_in[5];
  const float* mWhh_f  = (const float*)d_in[6];
  const float* mbih_f  = (const float*)d_in[7];
  const float* mbhh_f  = (const float*)d_in[8];
  const float* mWih_b  = (const float*)d_in[9];
  const float* mWhh_b  = (const float*)d_in[10];
  const float* mbih_b  = (const float*)d_in[11];
  const float* mbhh_b  = (const float*)d_in[12];
  const float* hWih_f  = (const float*)d_in[13];
  const float* hWhh_f  = (const float*)d_in[14];
  const float* hbih_f  = (const float*)d_in[15];
  const float* hbhh_f  = (const float*)d_in[16];
  const float* hWih_b  = (const float*)d_in[17];
  const float* hWhh_b  = (const float*)d_in[18];
  const float* hbih_b  = (const float*)d_in[19];
  const float* hbhh_b  = (const float*)d_in[20];
  const float* Wq      = (const float*)d_in[21];
  const float* bq      = (const float*)d_in[22];
  const float* Wv      = (const float*)d_in[23];
  const float* bv      = (const float*)d_in[24];
  const float* Wp      = (const float*)d_in[25];
  const float* bp      = (const float*)d_in[26];
  const float* Wk      = (const float*)d_in[27];
  const float* bk      = (const float*)d_in[28];
  float* ws  = (float*)d_ws;
  float* out = (float*)d_out;

  auto tp = [&](const float* src, float* dst, int R, int Csrc, int c0, int Cn) {
    const int n = R * Cn;
    k_transpose<<<(n + 255) / 256, 256, 0, stream>>>(src, dst, R, Csrc, c0, Cn);
  };
  tp(mWih_f, ws + OFF_MWIHT,               kGM, kDIN, 0, kDIN);
  tp(mWih_b, ws + OFF_MWIHT + kDIN * kGM,  kGM, kDIN, 0, kDIN);
  tp(mWhh_f, ws + OFF_MWHHT,               kGM, kHM,  0, kHM);
  tp(mWhh_b, ws + OFF_MWHHT + kHM * kGM,   kGM, kHM,  0, kHM);
  tp(hWih_f, ws + OFF_HWIHT,               kGH, kD2,  0, kD2);
  tp(hWih_b, ws + OFF_HWIHT + kD2 * kGH,   kGH, kD2,  0, kD2);
  tp(hWhh_f, ws + OFF_HWHHT,               kGH, kHH,  0, kHH);
  tp(hWhh_b, ws + OFF_HWHHT + kHH * kGH,   kGH, kHH,  0, kHH);
  k_pt<<<256, 256, 0, stream>>>(Wq, Wv, ws + OFF_PT);
  k_small<<<1, 256, 0, stream>>>(Wq, bq, Wv, bv, ws + OFF_U, ws + OFF_W, ws + OFF_C0, ws + OFF_ACC);

  k_main_gru<<<128, 512, 0, stream>>>(sent, ws + OFF_MWIHT, ws + OFF_MWHHT,
                                      mbih_f, mbhh_f, mbih_b, mbhh_b, ws + OFF_RNN);
  k_hier<<<512, 384, 0, stream>>>(ws + OFF_RNN, ws + OFF_HWIHT, ws + OFF_HWHHT,
                                  hbih_f, hbhh_f, hbih_b, hbhh_b, ws + OFF_HV);
  k_attn<<<256, 256, 0, stream>>>(ws + OFF_HV, ws + OFF_PT, ws + OFF_U, ws + OFF_W,
                                  ws + OFF_C0, ws + OFF_CTX);
  k_ctxlog<<<4096, 64, 0, stream>>>(ws + OFF_CTX, Wp, bp, Wk, bk,
                                    ws + OFF_CLOG, ws + OFF_KSLOGP);
  k_loss<<<256, 256, 0, stream>>>(ws + OFF_RNN, Wp, ws + OFF_CLOG, ws + OFF_KSLOGP,
                                  pitches, kss, ws + OFF_ACC);
  k_final<<<1, 1, 0, stream>>>(ws + OFF_ACC, out);
}

// Round 2
// 2130.955 us; speedup vs baseline: 1.5924x; 1.5924x over previous
//
#include <hip/hip_runtime.h>
#include <cstddef>

// ---- problem constants ----
constexpr int kT   = 1024;
constexpr int kB   = 64;
constexpr int kDIN = 17;
constexpr int kHM  = 150;   // main hidden (per dir)
constexpr int kGM  = 450;   // 3*kHM
constexpr int kHH  = 128;   // hier hidden (per dir)
constexpr int kM   = 16;    // measure length
constexpr int kD2  = 300;   // 2*kHM
constexpr int kDH2 = 256;   // 2*kHH
constexpr int kNP  = 35;
constexpr int kNK  = 15;

// ---- workspace layout (float offsets, all 16-float aligned) ----
constexpr size_t OFF_RNN    = 0;          // [1024][64][300]   19,660,800
constexpr size_t OFF_HV     = 19660800;   // [4096][16][256]   16,777,216
constexpr size_t OFF_CTX    = 36438016;   // [4096][256]        1,048,576
constexpr size_t OFF_PT     = 37486592;   // [256][256]            65,536
constexpr size_t OFF_U      = 37552128;   // [256]
constexpr size_t OFF_W      = 37552384;   // [256]
constexpr size_t OFF_C0     = 37552640;   // [16]
constexpr size_t OFF_ACC    = 37552656;   // [16] (sp,cp,sk,ck)
constexpr size_t OFF_KSLOGP = 37552672;   // [4096][15]            61,440
constexpr size_t OFF_CLOG   = 37614112;   // [4096][35]           143,360
constexpr size_t OFF_MWIHT  = 37757472;   // [2][17][450]          15,312
constexpr size_t OFF_MWHHT  = 37772784;   // [2][150][450]        135,008
constexpr size_t OFF_BPACK  = 37907792;   // ushort [2][24][14][64][8] = 344,064 us = 172,032 f
// total < 38.1M floats = ~152.4 MB

typedef __bf16 bf16x8 __attribute__((ext_vector_type(8)));
typedef float f32x4 __attribute__((ext_vector_type(4)));

__device__ __forceinline__ unsigned short f2bf(float f) {
  unsigned u = __float_as_uint(f);
  u += 0x7FFFu + ((u >> 16) & 1u);   // round-to-nearest-even
  return (unsigned short)(u >> 16);
}
__device__ __forceinline__ float sigm(float x) { return 1.f / (1.f + __expf(-x)); }

// ---------------------------------------------------------------------------
// generic (sub-)transpose: dst[c][r] = src[r][c0 + c]; dst is [Cn][R]
__global__ void k_transpose(const float* __restrict__ src, float* __restrict__ dst,
                            int R, int Csrc, int c0, int Cn) {
  int i = blockIdx.x * blockDim.x + threadIdx.x;
  if (i < R * Cn) {
    int r = i / Cn, c = i - r * Cn;
    dst[c * R + r] = src[r * Csrc + c0 + c];
  }
}

// PT[e][c] = sum_a Wq[a][c]*Wv[a][e]   (= (Wq^T Wv)[c][e])
__global__ void k_pt(const float* __restrict__ Wq, const float* __restrict__ Wv,
                     float* __restrict__ PT) {
  const int e = blockIdx.x, c = threadIdx.x;
  float acc = 0.f;
  for (int a = 0; a < 256; a++) acc += Wq[a * 256 + c] * Wv[a * 256 + e];
  PT[e * 256 + c] = acc;
}

__global__ void k_small(const float* __restrict__ Wq, const float* __restrict__ bq,
                        const float* __restrict__ Wv, const float* __restrict__ bv,
                        float* __restrict__ u, float* __restrict__ w,
                        float* __restrict__ c0, float* __restrict__ acc) {
  const int a = threadIdx.x; // 256
  float us = 0.f, ws = 0.f;
  for (int j = 0; j < 256; j++) {
    us += Wq[j * 256 + a] * bv[j];
    ws += bq[j] * Wv[j * 256 + a];
  }
  u[a] = us; w[a] = ws;
  if (a == 0) {
    float c = 0.f;
    for (int j = 0; j < 256; j++) c += bq[j] * bv[j];
    c0[0] = c;
    acc[0] = acc[1] = acc[2] = acc[3] = 0.f;
  }
}

// ---------------------------------------------------------------------------
// Repack hier weights into bf16 MFMA B-fragment order:
// bpack[d][nt(24)][kt(14)][lane(64)][j(8)];  B[k][n], n=nt*16+(lane&15),
// k = kt*32 + (lane>>4)*8 + j.  k<300 -> Wih col k; 300..319 -> 0 (pad);
// k>=320 -> Whh col k-320.
__global__ void k_repack(const float* __restrict__ hWih_f, const float* __restrict__ hWhh_f,
                         const float* __restrict__ hWih_b, const float* __restrict__ hWhh_b,
                         unsigned short* __restrict__ bpack) {
  const int bid = blockIdx.x;           // 2*24*14 = 672
  const int kt = bid % 14;
  const int nt = (bid / 14) % 24;
  const int d  = bid / (14 * 24);
  const float* Wih = d ? hWih_b : hWih_f;   // [384][300]
  const float* Whh = d ? hWhh_b : hWhh_f;   // [384][128]
  const int lane = threadIdx.x;
  const int n = nt * 16 + (lane & 15);
  const int kbase = kt * 32 + (lane >> 4) * 8;
  unsigned short* dst = bpack + ((((size_t)d * 24 + nt) * 14 + kt) * 64 + lane) * 8;
#pragma unroll
  for (int j = 0; j < 8; j++) {
    const int k = kbase + j;
    float f = 0.f;
    if (k < 300) f = Wih[n * 300 + k];
    else if (k >= 320) f = Whh[n * 128 + (k - 320)];
    dst[j] = f2bf(f);
  }
}

// ---------------------------------------------------------------------------
// Main bi-GRU: one block per (batch, dir). Weights in registers (thread=gate),
// h broadcast from LDS. 1024 sequential steps, 2 barriers/step.
__global__ __launch_bounds__(512, 2) void k_main_gru(
    const float* __restrict__ x,      // [1024][64][17]
    const float* __restrict__ WihT,   // [2][17][450]
    const float* __restrict__ WhhT,   // [2][150][450]
    const float* __restrict__ bihf, const float* __restrict__ bhhf,
    const float* __restrict__ bihb, const float* __restrict__ bhhb,
    float* __restrict__ rnn)          // [1024][64][300]
{
  const int d = blockIdx.x & 1;
  const int b = blockIdx.x >> 1;
  const int g = threadIdx.x;
  __shared__ __align__(16) float h_s[152];
  __shared__ __align__(16) float x_s[2][20];
  __shared__ float Ssum[300];
  __shared__ float INs[152];
  __shared__ float HNs[152];
  float wih[20], whh[152];
  float bi = 0.f, bh = 0.f;
  const float* WihTd = WihT + (size_t)d * (kDIN * kGM);
  const float* WhhTd = WhhT + (size_t)d * (kHM * kGM);
  if (g < kGM) {
#pragma unroll
    for (int k = 0; k < kDIN; k++) wih[k] = WihTd[k * kGM + g];
    wih[17] = wih[18] = wih[19] = 0.f;
#pragma unroll
    for (int k = 0; k < kHM; k++) whh[k] = WhhTd[k * kGM + g];
    whh[150] = whh[151] = 0.f;
    bi = d ? bihb[g] : bihf[g];
    bh = d ? bhhb[g] : bhhf[g];
  }
  if (g < 152) h_s[g] = 0.f;
  if (g < kDIN) {
    int t0 = d ? (kT - 1) : 0;
    x_s[0][g] = x[(t0 * kB + b) * kDIN + g];
  }
  if (g >= 64 && g < 67) { x_s[0][17 + (g - 64)] = 0.f; x_s[1][17 + (g - 64)] = 0.f; }
  __syncthreads();

  for (int t = 0; t < kT; t++) {
    const int tx = d ? (kT - 1 - t) : t;
    const int buf = t & 1;
    if (g < kGM) {
      float a0 = 0.f, a1 = 0.f, a2 = 0.f, a3 = 0.f;
#pragma unroll
      for (int k = 0; k < 152; k += 4) {
        const float4 hq = *(const float4*)&h_s[k];
        a0 += whh[k] * hq.x; a1 += whh[k + 1] * hq.y;
        a2 += whh[k + 2] * hq.z; a3 += whh[k + 3] * hq.w;
      }
      const float ah = (a0 + a1) + (a2 + a3) + bh;
      float i0 = 0.f, i1 = 0.f, i2 = 0.f, i3 = 0.f;
#pragma unroll
      for (int k = 0; k < 20; k += 4) {
        const float4 xq = *(const float4*)&x_s[buf][k];
        i0 += wih[k] * xq.x; i1 += wih[k + 1] * xq.y;
        i2 += wih[k + 2] * xq.z; i3 += wih[k + 3] * xq.w;
      }
      const float ai = (i0 + i1) + (i2 + i3) + bi;
      if (g < 300) Ssum[g] = ai + ah;
      else { INs[g - 300] = ai; HNs[g - 300] = ah; }
    }
    __syncthreads();
    if (t + 1 < kT && g >= 256 && g < 256 + kDIN) {
      const int tn = d ? (kT - 2 - t) : (t + 1);
      x_s[buf ^ 1][g - 256] = x[(tn * kB + b) * kDIN + (g - 256)];
    }
    if (g < kHM) {
      const float r = sigm(Ssum[g]);
      const float z = sigm(Ssum[150 + g]);
      const float n = tanhf(INs[g] + r * HNs[g]);
      const float hn = (1.f - z) * n + z * h_s[g];
      h_s[g] = hn;
      rnn[(tx * kB + b) * kD2 + d * kHM + g] = hn;
    }
    __syncthreads();
  }
}

// ---------------------------------------------------------------------------
// Hier bi-GRU via bf16 MFMA 16x16x32. Block = (dir, 16 bn rows), 256 thr = 4
// waves. Wave w owns n-tiles {w, w+4, ..., w+20}: tiles 0-7=r, 8-15=z,
// 16-23=n gates -> (r,z,n) of a hidden unit land in the SAME lane.
// n-gate keeps separate x-K / h-K accumulators (GRU needs r*hn).
__global__ __launch_bounds__(256) void k_hier_mfma(
    const float* __restrict__ rnn,             // [1024][64][300] = [n(64)*16+m][b][300] view
    const unsigned short* __restrict__ bpack,  // [2][24][14][64][8]
    const float* __restrict__ bihf, const float* __restrict__ bhhf,
    const float* __restrict__ bihb, const float* __restrict__ bhhb,
    float* __restrict__ hv)                    // [4096][16][256]
{
  const int d = blockIdx.x & 1;
  const int bn0 = (blockIdx.x >> 1) * 16;
  const int tid = threadIdx.x;
  const int w = tid >> 6;
  const int lane = tid & 63;
  const int q = lane >> 4, col = lane & 15;

  __shared__ __align__(16) unsigned short x_s[2][16][328]; // bf16, K-pad 300..319 = 0
  __shared__ __align__(16) unsigned short h_s[16][136];    // bf16 h for MFMA
  __shared__ __align__(16) float h32[16][136];             // fp32 h for z*h_old

  for (int i = tid; i < 16 * 136; i += 256) { ((unsigned short*)h_s)[i] = 0; ((float*)h32)[i] = 0.f; }
  for (int i = tid; i < 2 * 16 * 28; i += 256) {
    const int bb2 = i / (16 * 28), rr2 = (i / 28) & 15, cc2 = 300 + (i % 28);
    x_s[bb2][rr2][cc2] = 0;
  }
  const float* bih = d ? bihb : bihf;
  const float* bhh = d ? bhhb : bhhf;
  const int j0 = w * 16 + col, j1 = 64 + w * 16 + col;
  const float biR0 = bih[j0] + bhh[j0],             biR1 = bih[j1] + bhh[j1];
  const float biZ0 = bih[128 + j0] + bhh[128 + j0], biZ1 = bih[128 + j1] + bhh[128 + j1];
  const float biNX0 = bih[256 + j0], biNX1 = bih[256 + j1];
  const float biNH0 = bhh[256 + j0], biNH1 = bhh[256 + j1];

  { // stage x for step 0
    const int mx0 = d ? 15 : 0;
    for (int i = tid; i < 16 * 300; i += 256) {
      const int r = i / 300, c = i - r * 300;
      const int bn = bn0 + r, bb = bn >> 6, nn = bn & 63;
      x_s[0][r][c] = f2bf(rnn[((nn * 16 + mx0) * 64 + bb) * 300 + c]);
    }
  }
  __syncthreads();

  const unsigned short* bpd = bpack + (size_t)d * 24 * 14 * 64 * 8;

  for (int m = 0; m < kM; m++) {
    const int mx = d ? (15 - m) : m;
    const int buf = m & 1;
    // ---- MFMA phase ----
    f32x4 aR[2], aZ[2], aNX[2], aNH[2];
#pragma unroll
    for (int t = 0; t < 2; t++) {
      aR[t] = (f32x4)(0.f); aZ[t] = (f32x4)(0.f);
      aNX[t] = (f32x4)(0.f); aNH[t] = (f32x4)(0.f);
    }
#pragma unroll
    for (int kt = 0; kt < 14; kt++) {
      bf16x8 af;
      if (kt < 10) af = *(const bf16x8*)&x_s[buf][col][kt * 32 + q * 8];
      else         af = *(const bf16x8*)&h_s[col][(kt - 10) * 32 + q * 8];
#pragma unroll
      for (int t = 0; t < 6; t++) {
        const int nt = w + 4 * t;
        const bf16x8 bfr = *(const bf16x8*)&bpd[(((size_t)nt * 14 + kt) * 64 + lane) * 8];
        if (t < 2)        aR[t]      = __builtin_amdgcn_mfma_f32_16x16x32_bf16(af, bfr, aR[t], 0, 0, 0);
        else if (t < 4)   aZ[t - 2]  = __builtin_amdgcn_mfma_f32_16x16x32_bf16(af, bfr, aZ[t - 2], 0, 0, 0);
        else if (kt < 10) aNX[t - 4] = __builtin_amdgcn_mfma_f32_16x16x32_bf16(af, bfr, aNX[t - 4], 0, 0, 0);
        else              aNH[t - 4] = __builtin_amdgcn_mfma_f32_16x16x32_bf16(af, bfr, aNH[t - 4], 0, 0, 0);
      }
    }
    __syncthreads();  // all ds_reads of x_s/h_s done before h_s rewrite
    // ---- activation (in-register) + stage next x ----
#pragma unroll
    for (int jt = 0; jt < 2; jt++) {
      const int j = jt ? j1 : j0;
      const float bR = jt ? biR1 : biR0, bZ = jt ? biZ1 : biZ0;
      const float bNX = jt ? biNX1 : biNX0, bNH = jt ? biNH1 : biNH0;
#pragma unroll
      for (int i = 0; i < 4; i++) {
        const int row = q * 4 + i;
        const float rr = sigm(aR[jt][i] + bR);
        const float zz = sigm(aZ[jt][i] + bZ);
        const float hn = aNH[jt][i] + bNH;
        const float nn2 = tanhf(aNX[jt][i] + bNX + rr * hn);
        const float ho = h32[row][j];
        const float hnew = (1.f - zz) * nn2 + zz * ho;
        h32[row][j] = hnew;
        h_s[row][j] = f2bf(hnew);
        hv[((size_t)(bn0 + row) * kM + mx) * kDH2 + d * kHH + j] = hnew;
      }
    }
    if (m + 1 < kM) {
      const int mxn = d ? (15 - (m + 1)) : (m + 1);
      for (int i = tid; i < 16 * 300; i += 256) {
        const int r = i / 300, c = i - r * 300;
        const int bn = bn0 + r, bb = bn >> 6, nn = bn & 63;
        x_s[buf ^ 1][r][c] = f2bf(rnn[((nn * 16 + mxn) * 64 + bb) * 300 + c]);
      }
    }
    __syncthreads();
  }
}

// ---------------------------------------------------------------------------
// Attention (collapsed): one measure-group n per block (4096 blocks).
__global__ __launch_bounds__(256) void k_attn(
    const float* __restrict__ hv, const float* __restrict__ PT,
    const float* __restrict__ u, const float* __restrict__ w,
    const float* __restrict__ c0p, float* __restrict__ ctx) {
  const int tid = threadIdx.x; // 256
  const int n = blockIdx.x;
  __shared__ __align__(16) float hvs[16][256];
  __shared__ __align__(16) float Ts[16][260];
  __shared__ float As[16][17];
  __shared__ float uh[16], wh[16], SM[16];
  const float c0 = c0p[0];
  {
    const float4* src = (const float4*)(hv + (size_t)n * 4096);
    float4* dst = (float4*)hvs;
    for (int i = tid; i < 1024; i += 256) dst[i] = src[i];
  }
  __syncthreads();
  float acc[16];
#pragma unroll
  for (int m2 = 0; m2 < 16; m2++) acc[m2] = 0.f;
  for (int k = 0; k < 256; k += 4) {
    const float p0 = PT[(k + 0) * 256 + tid];
    const float p1 = PT[(k + 1) * 256 + tid];
    const float p2 = PT[(k + 2) * 256 + tid];
    const float p3 = PT[(k + 3) * 256 + tid];
#pragma unroll
    for (int m2 = 0; m2 < 16; m2++) {
      const float4 hq = *(const float4*)&hvs[m2][k];
      acc[m2] += p0 * hq.x + p1 * hq.y + p2 * hq.z + p3 * hq.w;
    }
  }
#pragma unroll
  for (int m2 = 0; m2 < 16; m2++) Ts[m2][tid] = acc[m2];
  if (tid < 16) {
    float s = 0.f;
    for (int a = 0; a < 256; a++) s += u[a] * hvs[tid][a];
    uh[tid] = s;
  } else if (tid < 32) {
    float s = 0.f;
    for (int a = 0; a < 256; a++) s += w[a] * hvs[tid - 16][a];
    wh[tid - 16] = s;
  }
  __syncthreads();
  const int l = tid >> 4, mm = tid & 15;
  float sc = c0 + uh[l] + wh[mm];
  for (int a = 0; a < 256; a += 4) {
    const float4 hq = *(const float4*)&hvs[l][a];
    const float4 tq = *(const float4*)&Ts[mm][a];
    sc += hq.x * tq.x + hq.y * tq.y + hq.z * tq.z + hq.w * tq.w;
  }
  float mxv = sc;
#pragma unroll
  for (int o = 8; o >= 1; o >>= 1) mxv = fmaxf(mxv, __shfl_xor(mxv, o, 16));
  const float e = __expf(sc - mxv);
  float se = e;
#pragma unroll
  for (int o = 8; o >= 1; o >>= 1) se += __shfl_xor(se, o, 16);
  As[l][mm] = e / se;
  __syncthreads();
  if (tid < 16) {
    float s = 0.f;
    for (int l2 = 0; l2 < 16; l2++) s += As[l2][tid];
    SM[tid] = s;
  }
  __syncthreads();
  float cv = 0.f;
#pragma unroll
  for (int m2 = 0; m2 < 16; m2++) cv += SM[m2] * hvs[m2][tid];
  ctx[(size_t)n * 256 + tid] = cv;
}

// ---------------------------------------------------------------------------
__global__ void k_ctxlog(const float* __restrict__ ctx, const float* __restrict__ Wp,
                         const float* __restrict__ bp, const float* __restrict__ Wk,
                         const float* __restrict__ bk,
                         float* __restrict__ ctx_logits, float* __restrict__ ks_logp) {
  const int bn = blockIdx.x, lane = threadIdx.x; // 64 threads
  __shared__ __align__(16) float W2[35][260];
  __shared__ __align__(16) float Wks[15][260];
  __shared__ __align__(16) float cs[256];
  for (int i = lane; i < 35 * 256; i += 64) { const int j = i >> 8, k = i & 255; W2[j][k] = Wp[j * 556 + 300 + k]; }
  for (int i = lane; i < 15 * 256; i += 64) { const int j = i >> 8, k = i & 255; Wks[j][k] = Wk[j * 256 + k]; }
  for (int i = lane; i < 256; i += 64) cs[i] = ctx[(size_t)bn * 256 + i];
  __syncthreads();
  if (lane < 35) {
    float a0 = 0.f, a1 = 0.f, a2 = 0.f, a3 = 0.f;
    for (int k = 0; k < 256; k += 4) {
      const float4 wq = *(const float4*)&W2[lane][k];
      const float4 cq = *(const float4*)&cs[k];
      a0 += wq.x * cq.x; a1 += wq.y * cq.y; a2 += wq.z * cq.z; a3 += wq.w * cq.w;
    }
    ctx_logits[bn * kNP + lane] = (a0 + a1) + (a2 + a3) + bp[lane];
  }
  float kk = -1e30f;
  if (lane < 15) {
    float a0 = 0.f, a1 = 0.f, a2 = 0.f, a3 = 0.f;
    for (int k = 0; k < 256; k += 4) {
      const float4 wq = *(const float4*)&Wks[lane][k];
      const float4 cq = *(const float4*)&cs[k];
      a0 += wq.x * cq.x; a1 += wq.y * cq.y; a2 += wq.z * cq.z; a3 += wq.w * cq.w;
    }
    kk = (a0 + a1) + (a2 + a3) + bk[lane];
  }
  float mxv = kk;
#pragma unroll
  for (int o = 8; o >= 1; o >>= 1) mxv = fmaxf(mxv, __shfl_xor(mxv, o, 16));
  const float e = (lane < 15) ? __expf(kk - mxv) : 0.f;
  float se = e;
#pragma unroll
  for (int o = 8; o >= 1; o >>= 1) se += __shfl_xor(se, o, 16);
  if (lane < 15) ks_logp[bn * kNK + lane] = kk - mxv - __logf(se);
}

// ---------------------------------------------------------------------------
__global__ __launch_bounds__(256) void k_loss(
    const float* __restrict__ rnn, const float* __restrict__ Wp,
    const float* __restrict__ ctx_logits, const float* __restrict__ ks_logp,
    const int* __restrict__ pitches, const int* __restrict__ kss,
    float* __restrict__ acc) {
  __shared__ __align__(16) float W1[35][308];
  __shared__ __align__(16) float xrs[4][304];
  __shared__ float red[4][4];
  const int tid = threadIdx.x, w = tid >> 6, lane = tid & 63;
  for (int i = tid; i < 35 * 300; i += 256) {
    const int j = i / 300, k = i - j * 300;
    W1[j][k] = Wp[j * 556 + k];
  }
  __syncthreads();
  float sp = 0.f, cp = 0.f, sk = 0.f, ck = 0.f;
  for (int it = 0; it < 64; it++) {
    const int row = blockIdx.x * 256 + it * 4 + w; // row = t*64 + b
    const int t = row >> 6, b = row & 63;
    const float* rp = rnn + (size_t)row * kD2;
    for (int i = lane; i < kD2; i += 64) xrs[w][i] = rp[i];
    __syncthreads();
    const int bn = b * 64 + (t >> 4);
    float lg = -1e30f;
    if (lane < 35) {
      float a0 = 0.f, a1 = 0.f, a2 = 0.f, a3 = 0.f;
      for (int k = 0; k < kD2; k += 4) {
        const float4 wq = *(const float4*)&W1[lane][k];
        const float4 xq = *(const float4*)&xrs[w][k];
        a0 += wq.x * xq.x; a1 += wq.y * xq.y; a2 += wq.z * xq.z; a3 += wq.w * xq.w;
      }
      lg = (a0 + a1) + (a2 + a3) + ctx_logits[bn * kNP + lane];
    }
    float mxv = lg;
#pragma unroll
    for (int o = 32; o >= 1; o >>= 1) mxv = fmaxf(mxv, __shfl_xor(mxv, o, 64));
    const float e = (lane < 35) ? __expf(lg - mxv) : 0.f;
    float se = e;
#pragma unroll
    for (int o = 32; o >= 1; o >>= 1) se += __shfl_xor(se, o, 64);
    const int tp2 = pitches[row];
    if (tp2 != 34) { sp += (mxv + __logf(se)) - __shfl(lg, tp2, 64); cp += 1.f; }
    const int tk = kss[row];
    if (tk != 14) { sk -= ks_logp[bn * kNK + tk]; ck += 1.f; }
    __syncthreads();
  }
  if (lane == 0) { red[w][0] = sp; red[w][1] = cp; red[w][2] = sk; red[w][3] = ck; }
  __syncthreads();
  if (tid == 0) {
    float a0 = 0.f, a1 = 0.f, a2 = 0.f, a3 = 0.f;
    for (int q = 0; q < 4; q++) { a0 += red[q][0]; a1 += red[q][1]; a2 += red[q][2]; a3 += red[q][3]; }
    atomicAdd(&acc[0], a0); atomicAdd(&acc[1], a1);
    atomicAdd(&acc[2], a2); atomicAdd(&acc[3], a3);
  }
}

__global__ void k_final(const float* __restrict__ acc, float* __restrict__ out) {
  out[0] = acc[0] / fmaxf(acc[1], 1.f) + acc[2] / fmaxf(acc[3], 1.f);
}

// ---------------------------------------------------------------------------
extern "C" void kernel_launch(void* const* d_in, const int* in_sizes, int n_in,
                              void* d_out, int out_size, void* d_ws, size_t ws_size,
                              hipStream_t stream) {
  (void)in_sizes; (void)n_in; (void)out_size; (void)ws_size;
  const float* sent    = (const float*)d_in[0];
  const int*   pitches = (const int*)d_in[1];
  const int*   kss     = (const int*)d_in[2];
  const float* mWih_f  = (const float*)d_in[5];
  const float* mWhh_f  = (const float*)d_in[6];
  const float* mbih_f  = (const float*)d_in[7];
  const float* mbhh_f  = (const float*)d_in[8];
  const float* mWih_b  = (const float*)d_in[9];
  const float* mWhh_b  = (const float*)d_in[10];
  const float* mbih_b  = (const float*)d_in[11];
  const float* mbhh_b  = (const float*)d_in[12];
  const float* hWih_f  = (const float*)d_in[13];
  const float* hWhh_f  = (const float*)d_in[14];
  const float* hbih_f  = (const float*)d_in[15];
  const float* hbhh_f  = (const float*)d_in[16];
  const float* hWih_b  = (const float*)d_in[17];
  const float* hWhh_b  = (const float*)d_in[18];
  const float* hbih_b  = (const float*)d_in[19];
  const float* hbhh_b  = (const float*)d_in[20];
  const float* Wq      = (const float*)d_in[21];
  const float* bq      = (const float*)d_in[22];
  const float* Wv      = (const float*)d_in[23];
  const float* bv      = (const float*)d_in[24];
  const float* Wp      = (const float*)d_in[25];
  const float* bp      = (const float*)d_in[26];
  const float* Wk      = (const float*)d_in[27];
  const float* bk      = (const float*)d_in[28];
  float* ws  = (float*)d_ws;
  float* out = (float*)d_out;

  auto tp = [&](const float* src, float* dst, int R, int Csrc, int c0, int Cn) {
    const int n = R * Cn;
    k_transpose<<<(n + 255) / 256, 256, 0, stream>>>(src, dst, R, Csrc, c0, Cn);
  };
  tp(mWih_f, ws + OFF_MWIHT,               kGM, kDIN, 0, kDIN);
  tp(mWih_b, ws + OFF_MWIHT + kDIN * kGM,  kGM, kDIN, 0, kDIN);
  tp(mWhh_f, ws + OFF_MWHHT,               kGM, kHM,  0, kHM);
  tp(mWhh_b, ws + OFF_MWHHT + kHM * kGM,   kGM, kHM,  0, kHM);
  k_repack<<<672, 64, 0, stream>>>(hWih_f, hWhh_f, hWih_b, hWhh_b,
                                   (unsigned short*)(ws + OFF_BPACK));
  k_pt<<<256, 256, 0, stream>>>(Wq, Wv, ws + OFF_PT);
  k_small<<<1, 256, 0, stream>>>(Wq, bq, Wv, bv, ws + OFF_U, ws + OFF_W, ws + OFF_C0, ws + OFF_ACC);

  k_main_gru<<<128, 512, 0, stream>>>(sent, ws + OFF_MWIHT, ws + OFF_MWHHT,
                                      mbih_f, mbhh_f, mbih_b, mbhh_b, ws + OFF_RNN);
  k_hier_mfma<<<512, 256, 0, stream>>>(ws + OFF_RNN, (const unsigned short*)(ws + OFF_BPACK),
                                       hbih_f, hbhh_f, hbih_b, hbhh_b, ws + OFF_HV);
  k_attn<<<4096, 256, 0, stream>>>(ws + OFF_HV, ws + OFF_PT, ws + OFF_U, ws + OFF_W,
                                   ws + OFF_C0, ws + OFF_CTX);
  k_ctxlog<<<4096, 64, 0, stream>>>(ws + OFF_CTX, Wp, bp, Wk, bk,
                                    ws + OFF_CLOG, ws + OFF_KSLOGP);
  k_loss<<<256, 256, 0, stream>>>(ws + OFF_RNN, Wp, ws + OFF_CLOG, ws + OFF_KSLOGP,
                                  pitches, kss, ws + OFF_ACC);
  k_final<<<1, 1, 0, stream>>>(ws + OFF_ACC, out);
}

// Round 3
// 1629.298 us; speedup vs baseline: 2.0827x; 1.3079x over previous
//
#include <hip/hip_runtime.h>
#include <cstddef>

// ---- problem constants ----
constexpr int kT   = 1024;
constexpr int kB   = 64;
constexpr int kDIN = 17;
constexpr int kHM  = 150;   // main hidden (per dir)
constexpr int kHH  = 128;   // hier hidden (per dir)
constexpr int kM   = 16;    // measure length
constexpr int kD2  = 300;   // 2*kHM
constexpr int kDH2 = 256;   // 2*kHH
constexpr int kNP  = 35;
constexpr int kNK  = 15;

// ---- workspace layout (float offsets, all 16-float aligned) ----
constexpr size_t OFF_RNN    = 0;          // [1024][64][300]   19,660,800
constexpr size_t OFF_HV     = 19660800;   // [4096][16][256]   16,777,216
constexpr size_t OFF_CTX    = 36438016;   // [4096][256]        1,048,576
constexpr size_t OFF_PT     = 37486592;   // [256][256]            65,536
constexpr size_t OFF_U      = 37552128;   // [256]
constexpr size_t OFF_W      = 37552384;   // [256]
constexpr size_t OFF_C0     = 37552640;   // [16]
constexpr size_t OFF_ACC    = 37552656;   // [16] (sp,cp,sk,ck)
constexpr size_t OFF_KSLOGP = 37552672;   // [4096][15]            61,440
constexpr size_t OFF_CLOG   = 37614112;   // [4096][35]           143,360
constexpr size_t OFF_BPACKM = 37757472;   // ushort [2][30][6][64][8] = 184,320 us = 92,160 f
constexpr size_t OFF_BPACK  = 37907792;   // ushort [2][24][14][64][8] = 344,064 us = 172,032 f
// total < 38.1M floats = ~152.4 MB

typedef __bf16 bf16x8 __attribute__((ext_vector_type(8)));
typedef float f32x4 __attribute__((ext_vector_type(4)));

__device__ __forceinline__ unsigned short f2bf(float f) {
  unsigned u = __float_as_uint(f);
  u += 0x7FFFu + ((u >> 16) & 1u);   // round-to-nearest-even
  return (unsigned short)(u >> 16);
}
__device__ __forceinline__ float sigm(float x) { return 1.f / (1.f + __expf(-x)); }

// PT[e][c] = sum_a Wq[a][c]*Wv[a][e]   (= (Wq^T Wv)[c][e])
__global__ void k_pt(const float* __restrict__ Wq, const float* __restrict__ Wv,
                     float* __restrict__ PT) {
  const int e = blockIdx.x, c = threadIdx.x;
  float acc = 0.f;
  for (int a = 0; a < 256; a++) acc += Wq[a * 256 + c] * Wv[a * 256 + e];
  PT[e * 256 + c] = acc;
}

__global__ void k_small(const float* __restrict__ Wq, const float* __restrict__ bq,
                        const float* __restrict__ Wv, const float* __restrict__ bv,
                        float* __restrict__ u, float* __restrict__ w,
                        float* __restrict__ c0, float* __restrict__ acc) {
  const int a = threadIdx.x; // 256
  float us = 0.f, ws = 0.f;
  for (int j = 0; j < 256; j++) {
    us += Wq[j * 256 + a] * bv[j];
    ws += bq[j] * Wv[j * 256 + a];
  }
  u[a] = us; w[a] = ws;
  if (a == 0) {
    float c = 0.f;
    for (int j = 0; j < 256; j++) c += bq[j] * bv[j];
    c0[0] = c;
    acc[0] = acc[1] = acc[2] = acc[3] = 0.f;
  }
}

// ---------------------------------------------------------------------------
// Repack hier weights into bf16 MFMA B-fragment order:
// bpack[d][nt(24)][kt(14)][lane(64)][j(8)];  B[k][n], n=nt*16+(lane&15),
// k = kt*32 + (lane>>4)*8 + j.  k<300 -> Wih col k; 300..319 -> 0 (pad);
// k>=320 -> Whh col k-320.
__global__ void k_repack(const float* __restrict__ hWih_f, const float* __restrict__ hWhh_f,
                         const float* __restrict__ hWih_b, const float* __restrict__ hWhh_b,
                         unsigned short* __restrict__ bpack) {
  const int bid = blockIdx.x;           // 2*24*14 = 672
  const int kt = bid % 14;
  const int nt = (bid / 14) % 24;
  const int d  = bid / (14 * 24);
  const float* Wih = d ? hWih_b : hWih_f;   // [384][300]
  const float* Whh = d ? hWhh_b : hWhh_f;   // [384][128]
  const int lane = threadIdx.x;
  const int n = nt * 16 + (lane & 15);
  const int kbase = kt * 32 + (lane >> 4) * 8;
  unsigned short* dst = bpack + ((((size_t)d * 24 + nt) * 14 + kt) * 64 + lane) * 8;
#pragma unroll
  for (int j = 0; j < 8; j++) {
    const int k = kbase + j;
    float f = 0.f;
    if (k < 300) f = Wih[n * 300 + k];
    else if (k >= 320) f = Whh[n * 128 + (k - 320)];
    dst[j] = f2bf(f);
  }
}

// ---------------------------------------------------------------------------
// Repack MAIN-GRU weights into bf16 B-fragments with reordered gate slots:
// slot s (0..479): type = s/160 (r,z,n), j = s%160 (hidden, valid j<150).
// K: kt 0..4 -> h index kt*32+(lane>>4)*8+jj (valid <150, Whh);
//    kt 5    -> x index (lane>>4)*8+jj (valid <17, Wih).
// bpackM[d][gt(30)][kt(6)][lane(64)][jj(8)]
__global__ void k_repack_main(const float* __restrict__ mWih_f, const float* __restrict__ mWhh_f,
                              const float* __restrict__ mWih_b, const float* __restrict__ mWhh_b,
                              unsigned short* __restrict__ bpackM) {
  const int bid = blockIdx.x;          // 2*30*6 = 360
  const int kt = bid % 6;
  const int gt = (bid / 6) % 30;
  const int d  = bid / 180;
  const float* Wih = d ? mWih_b : mWih_f;  // [450][17]
  const float* Whh = d ? mWhh_b : mWhh_f;  // [450][150]
  const int lane = threadIdx.x;
  const int slot = gt * 16 + (lane & 15);
  const int type = slot / 160, j = slot - type * 160;
  const int row = type * 150 + j;
  const bool valid = (j < 150);
  const int kbase = (lane >> 4) * 8;
  unsigned short* dst = bpackM + ((((size_t)d * 30 + gt) * 6 + kt) * 64 + lane) * 8;
#pragma unroll
  for (int jj = 0; jj < 8; jj++) {
    float f = 0.f;
    if (valid) {
      if (kt < 5) {
        const int k = kt * 32 + kbase + jj;
        if (k < 150) f = Whh[row * 150 + k];
      } else {
        const int k = kbase + jj;
        if (k < 17) f = Wih[row * 17 + k];
      }
    }
    dst[jj] = f2bf(f);
  }
}

// ---------------------------------------------------------------------------
// Main bi-GRU via M=1 MFMA. One block per (batch, dir), 640 threads = 10 waves.
// Wave w owns gate-tiles {w, 10+w, 20+w} = (r,z,n) for hidden j = w*16+lane
// -> activation fully in-register, h_old in a register. A-operand = bf16
// [h(160) | x(32)] broadcast to all 16 M-rows (D rows all equal). Double-
// buffered LDS A-vector -> ONE barrier per step.
__global__ __launch_bounds__(640, 3) void k_main_gru_mfma(
    const float* __restrict__ x,               // [1024][64][17]
    const unsigned short* __restrict__ bpackM, // [2][30][6][64][8]
    const float* __restrict__ bihf, const float* __restrict__ bhhf,
    const float* __restrict__ bihb, const float* __restrict__ bhhb,
    float* __restrict__ rnn)                   // [1024][64][300]
{
  const int d = blockIdx.x & 1, b = blockIdx.x >> 1;
  const int tid = threadIdx.x, w = tid >> 6, lane = tid & 63;
  const int col = lane & 15;
  const int q8 = (lane >> 4) * 8;
  __shared__ __align__(16) unsigned short hx[2][192]; // [0..159]=h (150 valid), [160..191]=x (17 valid)
  for (int i = tid; i < 2 * 192; i += 640) ((unsigned short*)hx)[i] = 0;

  const float* bih = d ? bihb : bihf;
  const float* bhh = d ? bhhb : bhhf;
  const int j = w * 16 + col;
  const bool actv = (lane < 16) && (j < 150);
  float br = 0.f, bz = 0.f, bnx = 0.f, bnh = 0.f;
  if (actv) {
    br  = bih[j] + bhh[j];
    bz  = bih[150 + j] + bhh[150 + j];
    bnx = bih[300 + j];
    bnh = bhh[300 + j];
  }
  // weight fragments: 3 gate-tiles x 6 kt = 72 VGPRs
  bf16x8 bw[3][6];
  const unsigned short* bp = bpackM + (size_t)d * 30 * 6 * 64 * 8;
  const int gts[3] = { w, 10 + w, 20 + w };
#pragma unroll
  for (int gi = 0; gi < 3; gi++)
#pragma unroll
    for (int kt = 0; kt < 6; kt++)
      bw[gi][kt] = *(const bf16x8*)&bp[(((size_t)gts[gi] * 6 + kt) * 64 + lane) * 8];

  // stage x_0
  if (w == 1 && lane >= 16 && lane < 33) {
    const int i = lane - 16;
    const int t0 = d ? (kT - 1) : 0;
    hx[0][160 + i] = f2bf(x[(t0 * kB + b) * kDIN + i]);
  }
  float h_old = 0.f;
  __syncthreads();

  for (int t = 0; t < kT; t++) {
    const int buf = t & 1;
    // prefetch x_{t+1} into the other buffer (no hazard: different buffer)
    if (w == 1 && lane >= 16 && lane < 33 && t + 1 < kT) {
      const int i = lane - 16;
      const int tn = d ? (kT - 2 - t) : (t + 1);
      hx[buf ^ 1][160 + i] = f2bf(x[(tn * kB + b) * kDIN + i]);
    }
    f32x4 aR = (f32x4)(0.f), aZ = (f32x4)(0.f), aNH = (f32x4)(0.f), aNX = (f32x4)(0.f);
#pragma unroll
    for (int kt = 0; kt < 6; kt++) {
      const bf16x8 af = *(const bf16x8*)&hx[buf][kt * 32 + q8];
      aR = __builtin_amdgcn_mfma_f32_16x16x32_bf16(af, bw[0][kt], aR, 0, 0, 0);
      aZ = __builtin_amdgcn_mfma_f32_16x16x32_bf16(af, bw[1][kt], aZ, 0, 0, 0);
      if (kt < 5) aNH = __builtin_amdgcn_mfma_f32_16x16x32_bf16(af, bw[2][kt], aNH, 0, 0, 0);
      else        aNX = __builtin_amdgcn_mfma_f32_16x16x32_bf16(af, bw[2][5], aNX, 0, 0, 0);
    }
    if (actv) {
      const float r = sigm(aR[0] + br);
      const float z = sigm(aZ[0] + bz);
      const float n = tanhf(aNX[0] + bnx + r * (aNH[0] + bnh));
      h_old = (1.f - z) * n + z * h_old;
      hx[buf ^ 1][j] = f2bf(h_old);
      const int tx = d ? (kT - 1 - t) : t;
      rnn[((size_t)tx * kB + b) * kD2 + d * kHM + j] = h_old;
    }
    __syncthreads();
  }
}

// ---------------------------------------------------------------------------
// Hier bi-GRU via bf16 MFMA 16x16x32 (validated round 2).
__global__ __launch_bounds__(256) void k_hier_mfma(
    const float* __restrict__ rnn,             // [1024][64][300]
    const unsigned short* __restrict__ bpack,  // [2][24][14][64][8]
    const float* __restrict__ bihf, const float* __restrict__ bhhf,
    const float* __restrict__ bihb, const float* __restrict__ bhhb,
    float* __restrict__ hv)                    // [4096][16][256]
{
  const int d = blockIdx.x & 1;
  const int bn0 = (blockIdx.x >> 1) * 16;
  const int tid = threadIdx.x;
  const int w = tid >> 6;
  const int lane = tid & 63;
  const int q = lane >> 4, col = lane & 15;

  __shared__ __align__(16) unsigned short x_s[2][16][328];
  __shared__ __align__(16) unsigned short h_s[16][136];
  __shared__ __align__(16) float h32[16][136];

  for (int i = tid; i < 16 * 136; i += 256) { ((unsigned short*)h_s)[i] = 0; ((float*)h32)[i] = 0.f; }
  for (int i = tid; i < 2 * 16 * 28; i += 256) {
    const int bb2 = i / (16 * 28), rr2 = (i / 28) & 15, cc2 = 300 + (i % 28);
    x_s[bb2][rr2][cc2] = 0;
  }
  const float* bih = d ? bihb : bihf;
  const float* bhh = d ? bhhb : bhhf;
  const int j0 = w * 16 + col, j1 = 64 + w * 16 + col;
  const float biR0 = bih[j0] + bhh[j0],             biR1 = bih[j1] + bhh[j1];
  const float biZ0 = bih[128 + j0] + bhh[128 + j0], biZ1 = bih[128 + j1] + bhh[128 + j1];
  const float biNX0 = bih[256 + j0], biNX1 = bih[256 + j1];
  const float biNH0 = bhh[256 + j0], biNH1 = bhh[256 + j1];

  {
    const int mx0 = d ? 15 : 0;
    for (int i = tid; i < 16 * 300; i += 256) {
      const int r = i / 300, c = i - r * 300;
      const int bn = bn0 + r, bb = bn >> 6, nn = bn & 63;
      x_s[0][r][c] = f2bf(rnn[((nn * 16 + mx0) * 64 + bb) * 300 + c]);
    }
  }
  __syncthreads();

  const unsigned short* bpd = bpack + (size_t)d * 24 * 14 * 64 * 8;

  for (int m = 0; m < kM; m++) {
    const int mx = d ? (15 - m) : m;
    const int buf = m & 1;
    f32x4 aR[2], aZ[2], aNX[2], aNH[2];
#pragma unroll
    for (int t = 0; t < 2; t++) {
      aR[t] = (f32x4)(0.f); aZ[t] = (f32x4)(0.f);
      aNX[t] = (f32x4)(0.f); aNH[t] = (f32x4)(0.f);
    }
#pragma unroll
    for (int kt = 0; kt < 14; kt++) {
      bf16x8 af;
      if (kt < 10) af = *(const bf16x8*)&x_s[buf][col][kt * 32 + q * 8];
      else         af = *(const bf16x8*)&h_s[col][(kt - 10) * 32 + q * 8];
#pragma unroll
      for (int t = 0; t < 6; t++) {
        const int nt = w + 4 * t;
        const bf16x8 bfr = *(const bf16x8*)&bpd[(((size_t)nt * 14 + kt) * 64 + lane) * 8];
        if (t < 2)        aR[t]      = __builtin_amdgcn_mfma_f32_16x16x32_bf16(af, bfr, aR[t], 0, 0, 0);
        else if (t < 4)   aZ[t - 2]  = __builtin_amdgcn_mfma_f32_16x16x32_bf16(af, bfr, aZ[t - 2], 0, 0, 0);
        else if (kt < 10) aNX[t - 4] = __builtin_amdgcn_mfma_f32_16x16x32_bf16(af, bfr, aNX[t - 4], 0, 0, 0);
        else              aNH[t - 4] = __builtin_amdgcn_mfma_f32_16x16x32_bf16(af, bfr, aNH[t - 4], 0, 0, 0);
      }
    }
    __syncthreads();
#pragma unroll
    for (int jt = 0; jt < 2; jt++) {
      const int j = jt ? j1 : j0;
      const float bR = jt ? biR1 : biR0, bZ = jt ? biZ1 : biZ0;
      const float bNX = jt ? biNX1 : biNX0, bNH = jt ? biNH1 : biNH0;
#pragma unroll
      for (int i = 0; i < 4; i++) {
        const int row = q * 4 + i;
        const float rr = sigm(aR[jt][i] + bR);
        const float zz = sigm(aZ[jt][i] + bZ);
        const float hn = aNH[jt][i] + bNH;
        const float nn2 = tanhf(aNX[jt][i] + bNX + rr * hn);
        const float ho = h32[row][j];
        const float hnew = (1.f - zz) * nn2 + zz * ho;
        h32[row][j] = hnew;
        h_s[row][j] = f2bf(hnew);
        hv[((size_t)(bn0 + row) * kM + mx) * kDH2 + d * kHH + j] = hnew;
      }
    }
    if (m + 1 < kM) {
      const int mxn = d ? (15 - (m + 1)) : (m + 1);
      for (int i = tid; i < 16 * 300; i += 256) {
        const int r = i / 300, c = i - r * 300;
        const int bn = bn0 + r, bb = bn >> 6, nn = bn & 63;
        x_s[buf ^ 1][r][c] = f2bf(rnn[((nn * 16 + mxn) * 64 + bb) * 300 + c]);
      }
    }
    __syncthreads();
  }
}

// ---------------------------------------------------------------------------
// Attention (collapsed): one measure-group n per block (4096 blocks).
__global__ __launch_bounds__(256) void k_attn(
    const float* __restrict__ hv, const float* __restrict__ PT,
    const float* __restrict__ u, const float* __restrict__ w,
    const float* __restrict__ c0p, float* __restrict__ ctx) {
  const int tid = threadIdx.x; // 256
  const int n = blockIdx.x;
  __shared__ __align__(16) float hvs[16][256];
  __shared__ __align__(16) float Ts[16][260];
  __shared__ float As[16][17];
  __shared__ float uh[16], wh[16], SM[16];
  const float c0 = c0p[0];
  {
    const float4* src = (const float4*)(hv + (size_t)n * 4096);
    float4* dst = (float4*)hvs;
    for (int i = tid; i < 1024; i += 256) dst[i] = src[i];
  }
  __syncthreads();
  float acc[16];
#pragma unroll
  for (int m2 = 0; m2 < 16; m2++) acc[m2] = 0.f;
  for (int k = 0; k < 256; k += 4) {
    const float p0 = PT[(k + 0) * 256 + tid];
    const float p1 = PT[(k + 1) * 256 + tid];
    const float p2 = PT[(k + 2) * 256 + tid];
    const float p3 = PT[(k + 3) * 256 + tid];
#pragma unroll
    for (int m2 = 0; m2 < 16; m2++) {
      const float4 hq = *(const float4*)&hvs[m2][k];
      acc[m2] += p0 * hq.x + p1 * hq.y + p2 * hq.z + p3 * hq.w;
    }
  }
#pragma unroll
  for (int m2 = 0; m2 < 16; m2++) Ts[m2][tid] = acc[m2];
  if (tid < 16) {
    float s = 0.f;
    for (int a = 0; a < 256; a++) s += u[a] * hvs[tid][a];
    uh[tid] = s;
  } else if (tid < 32) {
    float s = 0.f;
    for (int a = 0; a < 256; a++) s += w[a] * hvs[tid - 16][a];
    wh[tid - 16] = s;
  }
  __syncthreads();
  const int l = tid >> 4, mm = tid & 15;
  float sc = c0 + uh[l] + wh[mm];
  for (int a = 0; a < 256; a += 4) {
    const float4 hq = *(const float4*)&hvs[l][a];
    const float4 tq = *(const float4*)&Ts[mm][a];
    sc += hq.x * tq.x + hq.y * tq.y + hq.z * tq.z + hq.w * tq.w;
  }
  float mxv = sc;
#pragma unroll
  for (int o = 8; o >= 1; o >>= 1) mxv = fmaxf(mxv, __shfl_xor(mxv, o, 16));
  const float e = __expf(sc - mxv);
  float se = e;
#pragma unroll
  for (int o = 8; o >= 1; o >>= 1) se += __shfl_xor(se, o, 16);
  As[l][mm] = e / se;
  __syncthreads();
  if (tid < 16) {
    float s = 0.f;
    for (int l2 = 0; l2 < 16; l2++) s += As[l2][tid];
    SM[tid] = s;
  }
  __syncthreads();
  float cv = 0.f;
#pragma unroll
  for (int m2 = 0; m2 < 16; m2++) cv += SM[m2] * hvs[m2][tid];
  ctx[(size_t)n * 256 + tid] = cv;
}

// ---------------------------------------------------------------------------
__global__ void k_ctxlog(const float* __restrict__ ctx, const float* __restrict__ Wp,
                         const float* __restrict__ bp, const float* __restrict__ Wk,
                         const float* __restrict__ bk,
                         float* __restrict__ ctx_logits, float* __restrict__ ks_logp) {
  const int bn = blockIdx.x, lane = threadIdx.x; // 64 threads
  __shared__ __align__(16) float W2[35][260];
  __shared__ __align__(16) float Wks[15][260];
  __shared__ __align__(16) float cs[256];
  for (int i = lane; i < 35 * 256; i += 64) { const int j = i >> 8, k = i & 255; W2[j][k] = Wp[j * 556 + 300 + k]; }
  for (int i = lane; i < 15 * 256; i += 64) { const int j = i >> 8, k = i & 255; Wks[j][k] = Wk[j * 256 + k]; }
  for (int i = lane; i < 256; i += 64) cs[i] = ctx[(size_t)bn * 256 + i];
  __syncthreads();
  if (lane < 35) {
    float a0 = 0.f, a1 = 0.f, a2 = 0.f, a3 = 0.f;
    for (int k = 0; k < 256; k += 4) {
      const float4 wq = *(const float4*)&W2[lane][k];
      const float4 cq = *(const float4*)&cs[k];
      a0 += wq.x * cq.x; a1 += wq.y * cq.y; a2 += wq.z * cq.z; a3 += wq.w * cq.w;
    }
    ctx_logits[bn * kNP + lane] = (a0 + a1) + (a2 + a3) + bp[lane];
  }
  float kk = -1e30f;
  if (lane < 15) {
    float a0 = 0.f, a1 = 0.f, a2 = 0.f, a3 = 0.f;
    for (int k = 0; k < 256; k += 4) {
      const float4 wq = *(const float4*)&Wks[lane][k];
      const float4 cq = *(const float4*)&cs[k];
      a0 += wq.x * cq.x; a1 += wq.y * cq.y; a2 += wq.z * cq.z; a3 += wq.w * cq.w;
    }
    kk = (a0 + a1) + (a2 + a3) + bk[lane];
  }
  float mxv = kk;
#pragma unroll
  for (int o = 8; o >= 1; o >>= 1) mxv = fmaxf(mxv, __shfl_xor(mxv, o, 16));
  const float e = (lane < 15) ? __expf(kk - mxv) : 0.f;
  float se = e;
#pragma unroll
  for (int o = 8; o >= 1; o >>= 1) se += __shfl_xor(se, o, 16);
  if (lane < 15) ks_logp[bn * kNK + lane] = kk - mxv - __logf(se);
}

// ---------------------------------------------------------------------------
__global__ __launch_bounds__(256) void k_loss(
    const float* __restrict__ rnn, const float* __restrict__ Wp,
    const float* __restrict__ ctx_logits, const float* __restrict__ ks_logp,
    const int* __restrict__ pitches, const int* __restrict__ kss,
    float* __restrict__ acc) {
  __shared__ __align__(16) float W1[35][308];
  __shared__ __align__(16) float xrs[4][304];
  __shared__ float red[4][4];
  const int tid = threadIdx.x, w = tid >> 6, lane = tid & 63;
  for (int i = tid; i < 35 * 300; i += 256) {
    const int j = i / 300, k = i - j * 300;
    W1[j][k] = Wp[j * 556 + k];
  }
  __syncthreads();
  float sp = 0.f, cp = 0.f, sk = 0.f, ck = 0.f;
  for (int it = 0; it < 64; it++) {
    const int row = blockIdx.x * 256 + it * 4 + w; // row = t*64 + b
    const int t = row >> 6, b = row & 63;
    const float* rp = rnn + (size_t)row * kD2;
    for (int i = lane; i < kD2; i += 64) xrs[w][i] = rp[i];
    __syncthreads();
    const int bn = b * 64 + (t >> 4);
    float lg = -1e30f;
    if (lane < 35) {
      float a0 = 0.f, a1 = 0.f, a2 = 0.f, a3 = 0.f;
      for (int k = 0; k < kD2; k += 4) {
        const float4 wq = *(const float4*)&W1[lane][k];
        const float4 xq = *(const float4*)&xrs[w][k];
        a0 += wq.x * xq.x; a1 += wq.y * xq.y; a2 += wq.z * xq.z; a3 += wq.w * xq.w;
      }
      lg = (a0 + a1) + (a2 + a3) + ctx_logits[bn * kNP + lane];
    }
    float mxv = lg;
#pragma unroll
    for (int o = 32; o >= 1; o >>= 1) mxv = fmaxf(mxv, __shfl_xor(mxv, o, 64));
    const float e = (lane < 35) ? __expf(lg - mxv) : 0.f;
    float se = e;
#pragma unroll
    for (int o = 32; o >= 1; o >>= 1) se += __shfl_xor(se, o, 64);
    const int tp2 = pitches[row];
    if (tp2 != 34) { sp += (mxv + __logf(se)) - __shfl(lg, tp2, 64); cp += 1.f; }
    const int tk = kss[row];
    if (tk != 14) { sk -= ks_logp[bn * kNK + tk]; ck += 1.f; }
    __syncthreads();
  }
  if (lane == 0) { red[w][0] = sp; red[w][1] = cp; red[w][2] = sk; red[w][3] = ck; }
  __syncthreads();
  if (tid == 0) {
    float a0 = 0.f, a1 = 0.f, a2 = 0.f, a3 = 0.f;
    for (int q = 0; q < 4; q++) { a0 += red[q][0]; a1 += red[q][1]; a2 += red[q][2]; a3 += red[q][3]; }
    atomicAdd(&acc[0], a0); atomicAdd(&acc[1], a1);
    atomicAdd(&acc[2], a2); atomicAdd(&acc[3], a3);
  }
}

__global__ void k_final(const float* __restrict__ acc, float* __restrict__ out) {
  out[0] = acc[0] / fmaxf(acc[1], 1.f) + acc[2] / fmaxf(acc[3], 1.f);
}

// ---------------------------------------------------------------------------
extern "C" void kernel_launch(void* const* d_in, const int* in_sizes, int n_in,
                              void* d_out, int out_size, void* d_ws, size_t ws_size,
                              hipStream_t stream) {
  (void)in_sizes; (void)n_in; (void)out_size; (void)ws_size;
  const float* sent    = (const float*)d_in[0];
  const int*   pitches = (const int*)d_in[1];
  const int*   kss     = (const int*)d_in[2];
  const float* mWih_f  = (const float*)d_in[5];
  const float* mWhh_f  = (const float*)d_in[6];
  const float* mbih_f  = (const float*)d_in[7];
  const float* mbhh_f  = (const float*)d_in[8];
  const float* mWih_b  = (const float*)d_in[9];
  const float* mWhh_b  = (const float*)d_in[10];
  const float* mbih_b  = (const float*)d_in[11];
  const float* mbhh_b  = (const float*)d_in[12];
  const float* hWih_f  = (const float*)d_in[13];
  const float* hWhh_f  = (const float*)d_in[14];
  const float* hbih_f  = (const float*)d_in[15];
  const float* hbhh_f  = (const float*)d_in[16];
  const float* hWih_b  = (const float*)d_in[17];
  const float* hWhh_b  = (const float*)d_in[18];
  const float* hbih_b  = (const float*)d_in[19];
  const float* hbhh_b  = (const float*)d_in[20];
  const float* Wq      = (const float*)d_in[21];
  const float* bq      = (const float*)d_in[22];
  const float* Wv      = (const float*)d_in[23];
  const float* bv      = (const float*)d_in[24];
  const float* Wp      = (const float*)d_in[25];
  const float* bp      = (const float*)d_in[26];
  const float* Wk      = (const float*)d_in[27];
  const float* bk      = (const float*)d_in[28];
  float* ws  = (float*)d_ws;
  float* out = (float*)d_out;

  k_repack_main<<<360, 64, 0, stream>>>(mWih_f, mWhh_f, mWih_b, mWhh_b,
                                        (unsigned short*)(ws + OFF_BPACKM));
  k_repack<<<672, 64, 0, stream>>>(hWih_f, hWhh_f, hWih_b, hWhh_b,
                                   (unsigned short*)(ws + OFF_BPACK));
  k_pt<<<256, 256, 0, stream>>>(Wq, Wv, ws + OFF_PT);
  k_small<<<1, 256, 0, stream>>>(Wq, bq, Wv, bv, ws + OFF_U, ws + OFF_W, ws + OFF_C0, ws + OFF_ACC);

  k_main_gru_mfma<<<128, 640, 0, stream>>>(sent, (const unsigned short*)(ws + OFF_BPACKM),
                                           mbih_f, mbhh_f, mbih_b, mbhh_b, ws + OFF_RNN);
  k_hier_mfma<<<512, 256, 0, stream>>>(ws + OFF_RNN, (const unsigned short*)(ws + OFF_BPACK),
                                       hbih_f, hbhh_f, hbih_b, hbhh_b, ws + OFF_HV);
  k_attn<<<4096, 256, 0, stream>>>(ws + OFF_HV, ws + OFF_PT, ws + OFF_U, ws + OFF_W,
                                   ws + OFF_C0, ws + OFF_CTX);
  k_ctxlog<<<4096, 64, 0, stream>>>(ws + OFF_CTX, Wp, bp, Wk, bk,
                                    ws + OFF_CLOG, ws + OFF_KSLOGP);
  k_loss<<<256, 256, 0, stream>>>(ws + OFF_RNN, Wp, ws + OFF_CLOG, ws + OFF_KSLOGP,
                                  pitches, kss, ws + OFF_ACC);
  k_final<<<1, 1, 0, stream>>>(ws + OFF_ACC, out);
}